// Round 9
// baseline (288.924 us; speedup 1.0000x reference)
//
#include <hip/hip_runtime.h>
#include <math.h>

// ---------------------------------------------------------------------------
// HRSNN. R9: spike rows stored as ballot bitmasks. R8's k_hr was CU-LDS-pipe
// bound (~700 LDS wave-instrs/block; 60KB LDS -> 2 blocks/CU, 1.56 rounds).
// Scans emit each 60/20-wide spike row via ONE __ballot -> uint2/uint per
// row; conv60/fcskip read 1 b64/b32 per row (broadcast) and decode with
// (float)((m>>j)&1) + fmaf — operands and FMA order bit-identical to R8
// (decoded 0.0f/1.0f == stored floats). LDS 60->28KB -> 4 blocks/CU, one
// dispatch round. absmax must stay exactly 0.125.
// ---------------------------------------------------------------------------

namespace {
constexpr int TT = 51200;  // B*T
constexpr double TAU1d = 1.2231301601484298;  // exp(-1.5)+1
constexpr double TAU2d = 1.3678794411714423;  // exp(-1.0)+1  (== TAU4)
constexpr double TAU3d = 1.4493289641172216;  // exp(-0.8)+1

constexpr int LSTM_L = 32, LSTM_W = 96, LSTM_NCH = TT / LSTM_L;  // 1600
constexpr int HRL = 64;                  // hr-module output chunk length
constexpr int HR_NCH = TT / HRL;         // 800
constexpr int FB_L = 32, FB_W = 32, FB_NCH = 512 / FB_L;  // 16

// workspace layout (float offsets)
constexpr size_t OFF_PRE   = 0;         // 51200*40 (+320 over-read pad)
constexpr size_t OFF_HSEQ  = 2048320;   // 51200*10
constexpr size_t OFF_XIN2  = 3072000;   // 51200*20
constexpr size_t OFF_OUT2  = 4096000;   // 51200*10
constexpr size_t OFF_OUT3  = 4608320;   // 512*100*10
constexpr size_t OFF_FUSED = 5120320;   // 512*200
constexpr size_t OFF_STATS = 5222720;   // 512*2 doubles (8-byte aligned)
}  // namespace

__device__ __forceinline__ float rcp_nr(float d) {
  float r = __builtin_amdgcn_rcpf(d);
  return r * (2.0f - d * r);  // one Newton step: ~1ulp
}

// K1: pregate[(b*100+tt)*40+l] = sum_c x[b][c][tt]*wih[l][c] + bih[l]+bhh[l]
__global__ void __launch_bounds__(256) k_pregate(const float* __restrict__ x,
                                                 const float* __restrict__ wih,
                                                 const float* __restrict__ bih,
                                                 const float* __restrict__ bhh,
                                                 float* __restrict__ pre) {
  __shared__ __align__(16) float xs[6400];   // xs[c*100+tt]
  __shared__ __align__(16) float wT[2560];   // wT[c*40+l]
  __shared__ float bl[40];
  const int b = blockIdx.x;
  const int tid = threadIdx.x;
  for (int i = tid; i < 6400; i += 256) xs[i] = x[b * 6400 + i];  // coalesced
  for (int i = tid; i < 2560; i += 256) {
    const int c = i / 40;
    const int l = i - c * 40;
    wT[i] = wih[l * 64 + c];
  }
  if (tid < 40) bl[tid] = bih[tid] + bhh[tid];
  __syncthreads();
  if (tid >= 250) return;              // 25 tt-tiles x 10 l-tiles
  const int ttile = tid / 10;
  const int ltile = tid - ttile * 10;
  const int tt0 = ttile * 4;
  const int l0 = ltile * 4;
  float acc[4][4];
#pragma unroll
  for (int i = 0; i < 4; ++i)
#pragma unroll
    for (int j = 0; j < 4; ++j) acc[i][j] = bl[l0 + j];
#pragma unroll 8
  for (int c = 0; c < 64; ++c) {
    const float4 wv = *(const float4*)&wT[c * 40 + l0];
    const float4 xv = *(const float4*)&xs[c * 100 + tt0];
    const float xa[4] = {xv.x, xv.y, xv.z, xv.w};
    const float wa[4] = {wv.x, wv.y, wv.z, wv.w};
#pragma unroll
    for (int i = 0; i < 4; ++i)
#pragma unroll
      for (int j = 0; j < 4; ++j) acc[i][j] = fmaf(xa[i], wa[j], acc[i][j]);
  }
#pragma unroll
  for (int i = 0; i < 4; ++i) {
    float4 o;
    o.x = acc[i][0]; o.y = acc[i][1]; o.z = acc[i][2]; o.w = acc[i][3];
    *(float4*)&pre[(b * 100 + tt0 + i) * 40 + l0] = o;
  }
}

// K2: chunk-parallel LSTM (warm-up LSTM_W from (0,0) -> bit-exact merge).
__global__ void __launch_bounds__(64) k_lstm(const float* __restrict__ pre,
                                             const float* __restrict__ whh,
                                             float* __restrict__ hseq) {
  const int lane = threadIdx.x;
  const int l = lane < 40 ? lane : 0;
  float wh[10];
#pragma unroll
  for (int j = 0; j < 10; ++j) wh[j] = whh[l * 10 + j];
  const int jm = lane % 10;
  const bool is_g = (l >= 20) & (l < 30);
  const float sel = is_g ? 2.0f : -1.0f;
  const int outstart = blockIdx.x * LSTM_L;
  const int start = (outstart >= LSTM_W) ? outstart - LSTM_W : 0;  // mult of 32
  const int end = outstart + LSTM_L;
  float cst = 0.0f;
  float h[10];
#pragma unroll
  for (int j = 0; j < 10; ++j) h[j] = 0.0f;
  float pbuf[8];
#pragma unroll
  for (int i = 0; i < 8; ++i) pbuf[i] = pre[(start + i) * 40 + l];
#pragma unroll 8
  for (int t = start; t < end; ++t) {
    float g = pbuf[t & 7];
    pbuf[t & 7] = pre[(t + 8) * 40 + l];  // last chunk over-reads into pad
#pragma unroll
    for (int j = 0; j < 10; ++j) g = fmaf(h[j], wh[j], g);
    const float e = __expf(sel * g);
    const float r = rcp_nr(1.0f + e);
    const float act = is_g ? (1.0f - 2.0f * r) : r;
    const float ai = __shfl(act, jm);
    const float af = __shfl(act, jm + 10);
    const float ag = __shfl(act, jm + 20);
    const float ao = __shfl(act, jm + 30);
    cst = af * cst + ai * ag;
    const float hn = ao * (1.0f - 2.0f * rcp_nr(__expf(2.0f * cst) + 1.0f));
    if ((lane < 10) & (t >= outstart)) hseq[t * 10 + lane] = hn;
#pragma unroll
    for (int j = 0; j < 10; ++j)
      h[j] = __uint_as_float(__builtin_amdgcn_readlane(__float_as_uint(hn), j));
  }
}

// K3/K4: fused hr_module, 256 threads, spike rows as ballot masks.
template <int MODE, int O>
__global__ void __launch_bounds__(256) k_hr(const float* __restrict__ src,
                                            const float* __restrict__ sw,
                                            const float* __restrict__ sb,
                                            const float* __restrict__ cw,
                                            const float* __restrict__ cb,
                                            const float* __restrict__ fw,
                                            const float* __restrict__ fb,
                                            const float* __restrict__ skw,
                                            const float* __restrict__ skb,
                                            float* __restrict__ outp) {
  __shared__ __align__(16) float xin_s[128 * 20];
  // cbuf: MODE0 hs (128*10) before P1; c_s (96*20) P3->P4; P5 result after.
  __shared__ __align__(16) float cbuf_s[96 * 20];
  __shared__ __align__(8) uint2 hlm_s[96];   // lif3 spike masks (60 bits)
  __shared__ unsigned s4m_s[HRL];            // lifseq spike masks (20 bits)
  __shared__ __align__(16) float cw_s[1200];
  __shared__ __align__(16) float fw_s[O * 20];
  __shared__ __align__(16) float skw_s[O * 20];
  __shared__ __align__(16) float sw_s[MODE == 0 ? 200 : 4];
  __shared__ float cb_s[20];
  __shared__ float fb_s[O];
  __shared__ float skb_s[O];
  __shared__ float sb_s[20];

  const int tid = threadIdx.x;
  const int outstart = blockIdx.x * HRL;
  const int end = outstart + HRL;
  const int s2 = (outstart >= 32) ? outstart - 32 : 0;
  const int s1 = (s2 >= 32) ? s2 - 32 : 0;
  const int n1 = end - s1;  // <=128, multiple of 32
  const int n2 = end - s2;  // <=96

  // ---- stage (float4) ----
  for (int i = tid; i < 300; i += 256)
    ((float4*)cw_s)[i] = ((const float4*)cw)[i];
  for (int i = tid; i < O * 5; i += 256) {
    ((float4*)fw_s)[i] = ((const float4*)fw)[i];
    ((float4*)skw_s)[i] = ((const float4*)skw)[i];
  }
  if (tid < O) { fb_s[tid] = fb[tid]; skb_s[tid] = skb[tid]; }
  if (tid >= 32 && tid < 52) cb_s[tid - 32] = cb[tid - 32];
  if (MODE == 0) {
    for (int i = tid; i < 50; i += 256)
      ((float4*)sw_s)[i] = ((const float4*)sw)[i];
    if (tid >= 64 && tid < 84) sb_s[tid - 64] = sb[tid - 64];
    const float4* gsrc = (const float4*)(src + (size_t)s1 * 10);
    for (int i = tid; i < n1 * 10 / 4; i += 256) ((float4*)cbuf_s)[i] = gsrc[i];
  } else {
    const float4* gsrc = (const float4*)(src + (size_t)s1 * 20);
    for (int i = tid; i < n1 * 5; i += 256) ((float4*)xin_s)[i] = gsrc[i];
  }
  __syncthreads();

  // ---- P1: sconv -> xin_s (MODE 0). thread=(o,rg), weights in regs ----
  if (MODE == 0) {
    const int rg = tid / 20;
    const int o = tid - rg * 20;
    if (rg < 12) {
      float2 w[5];
      const float* wp = sw_s + o * 10;
#pragma unroll
      for (int q = 0; q < 5; ++q) w[q] = *(const float2*)&wp[q * 2];
      const float bias = sb_s[o];
      for (int rel = rg; rel < n1; rel += 12) {
        const float* hp = cbuf_s + rel * 10;  // broadcast across the 20 o-lanes
        float acc = bias;
#pragma unroll
        for (int q = 0; q < 5; ++q) {
          const float2 h = *(const float2*)&hp[q * 2];
          acc = fmaf(h.x, w[q].x, acc);
          acc = fmaf(h.y, w[q].y, acc);
        }
        xin_s[rel * 20 + o] = acc;
      }
    }
    __syncthreads();
  }

  // ---- P2: lif3 scan (wave 0, 60 chains) -> ballot masks ----
  if (tid < 64) {
    const int cid = tid < 60 ? tid : 0;
    const int f = cid / 3;
    const int k = cid - f * 3;
    const float tau = (k == 0) ? (float)TAU1d : (k == 1) ? (float)TAU2d : (float)TAU3d;
    const float rt = 1.0f / tau;
    const float th = (k == 0) ? 0.14f : (k == 1) ? 0.08f : 0.06f;
    float v = 0.0f;
#pragma unroll 4
    for (int t = s1; t < end; ++t) {
      const float x = xin_s[(t - s1) * 20 + f];
      v = fmaf(x - v, rt, v);
      const float sp = (v - th >= 0.0f) ? 1.0f : 0.0f;
      const unsigned long long m = __ballot(sp != 0.0f);
      if ((tid == 0) & (t >= s2)) {
        uint2 mm;
        mm.x = (unsigned)m;
        mm.y = (unsigned)(m >> 32) & 0x0FFFFFFFu;  // drop junk lanes 60-63
        hlm_s[t - s2] = mm;
      }
      v = (sp != 0.0f) ? 0.0f : v;
    }
  }
  __syncthreads();

  // ---- P3: conv60 -> cbuf_s. masks: 1 b64/row; decode bfe+cvt+fma ----
  {
    const int rg = tid / 20;
    const int o = tid - rg * 20;
    if (rg < 12) {
      float4 w[15];
      const float* wp = cw_s + o * 60;
#pragma unroll
      for (int q = 0; q < 15; ++q) w[q] = *(const float4*)&wp[q * 4];
      const float bias = cb_s[o];
      for (int rel = rg; rel < n2; rel += 12) {
        const uint2 m = hlm_s[rel];  // broadcast across the 20 o-lanes
        float acc = bias;
#pragma unroll
        for (int q = 0; q < 15; ++q) {
          const unsigned mm = (q < 8) ? m.x : m.y;
          const int sh = (q < 8) ? q * 4 : q * 4 - 32;
          acc = fmaf((float)((mm >> (sh + 0)) & 1u), w[q].x, acc);
          acc = fmaf((float)((mm >> (sh + 1)) & 1u), w[q].y, acc);
          acc = fmaf((float)((mm >> (sh + 2)) & 1u), w[q].z, acc);
          acc = fmaf((float)((mm >> (sh + 3)) & 1u), w[q].w, acc);
        }
        cbuf_s[rel * 20 + o] = acc;
      }
    }
  }
  __syncthreads();

  // ---- P4: lifseq scan (wave 0, 20 chains) -> ballot masks ----
  if (tid < 64) {
    const int f = tid < 20 ? tid : 0;
    const float rt = 1.0f / (float)TAU2d;
    float v = 0.0f;
#pragma unroll 4
    for (int t = s2; t < end; ++t) {
      const float x = cbuf_s[(t - s2) * 20 + f];
      v = fmaf(x - v, rt, v);
      const float sp = (v - 0.08f >= 0.0f) ? 1.0f : 0.0f;
      const unsigned long long m = __ballot(sp != 0.0f);
      if ((tid == 0) & (t >= outstart))
        s4m_s[t - outstart] = (unsigned)m & 0xFFFFFu;
      v = (sp != 0.0f) ? 0.0f : v;
    }
  }
  __syncthreads();

  // ---- P5: fcskip -> cbuf_s (c region dead), then coalesced global ----
  {
    constexpr int ORG = (O == 20) ? 12 : 25;
    const int rg = tid / O;
    const int o = tid - rg * O;
    const int xoff = outstart - s1;
    if (rg < ORG) {
      float4 fv[5], kv[5];
      const float* fwp = fw_s + o * 20;
      const float* swp = skw_s + o * 20;
#pragma unroll
      for (int q = 0; q < 5; ++q) {
        fv[q] = *(const float4*)&fwp[q * 4];
        kv[q] = *(const float4*)&swp[q * 4];
      }
      const float bias = fb_s[o] + skb_s[o];
      for (int rel = rg; rel < HRL; rel += ORG) {
        const unsigned sm = s4m_s[rel];              // broadcast
        const float* xi = xin_s + (xoff + rel) * 20; // broadcast rows
        float acc = bias;
#pragma unroll
        for (int q = 0; q < 5; ++q) {
          const float4 xv = *(const float4*)&xi[q * 4];
          acc = fmaf((float)((sm >> (q * 4 + 0)) & 1u), fv[q].x,
                     fmaf(xv.x, kv[q].x, acc));
          acc = fmaf((float)((sm >> (q * 4 + 1)) & 1u), fv[q].y,
                     fmaf(xv.y, kv[q].y, acc));
          acc = fmaf((float)((sm >> (q * 4 + 2)) & 1u), fv[q].z,
                     fmaf(xv.z, kv[q].z, acc));
          acc = fmaf((float)((sm >> (q * 4 + 3)) & 1u), fv[q].w,
                     fmaf(xv.w, kv[q].w, acc));
        }
        cbuf_s[rel * O + o] = acc;
      }
    }
  }
  __syncthreads();
  {
    float4* gout = (float4*)(outp + (size_t)outstart * O);
    for (int i = tid; i < HRL * O / 4; i += 256) gout[i] = ((float4*)cbuf_s)[i];
  }
}

// K5: final LIF over batch axis: 1000 chains, chunked over b (L=W=32).
__global__ void __launch_bounds__(256) k_flif(const float* __restrict__ out2,
                                              float* __restrict__ out3) {
  const int idx = blockIdx.x * 256 + threadIdx.x;
  if (idx >= FB_NCH * 1000) return;
  const int chunk = idx / 1000;
  const int chain = idx - chunk * 1000;
  const float rt = 1.0f / (float)TAU2d;
  const int outstart = chunk * FB_L;
  const int start = (outstart >= FB_W) ? outstart - FB_W : 0;
  const int end = outstart + FB_L;
  float v = 0.0f;
  float xb[4];
#pragma unroll
  for (int i = 0; i < 4; ++i) xb[i] = out2[(start + i) * 1000 + chain];
#pragma unroll 4
  for (int b = start; b < end; ++b) {
    const float x = xb[b & 3];
    xb[b & 3] = out2[(b + 4) * 1000 + chain];  // over-read harmless (unused)
    v = fmaf(x - v, rt, v);
    const float sp = (v - 0.08f >= 0.0f) ? 1.0f : 0.0f;
    if (b >= outstart) out3[b * 1000 + chain] = sp;
    v = (sp != 0.0f) ? 0.0f : v;
  }
}

// K6: dp -> avg -> fused; per-block (per-b) partial sum/sumsq in double.
__global__ void __launch_bounds__(256) k_fused(const float* __restrict__ out3,
                                               float* __restrict__ fused,
                                               double* __restrict__ stats) {
  __shared__ float dp_s[200];
  __shared__ float avg_s[20];
  __shared__ double red_s[8];
  const int b = blockIdx.x;
  const int tid = threadIdx.x;
  if (tid < 200) {
    const int f = tid / 20;
    const int seg = tid - f * 20;
    const float* base = out3 + b * 1000 + seg * 50 + f;
    dp_s[tid] = ((base[30] + base[40]) - (base[0] + base[10])) * 0.5f;
  }
  __syncthreads();
  if (tid < 20) {
    float s = 0.0f;
#pragma unroll
    for (int f = 0; f < 10; ++f) s += dp_s[f * 20 + tid];
    avg_s[tid] = s / 10.0f;
  }
  __syncthreads();
  float val = 0.0f;
  if (tid < 200) {
    val = dp_s[tid] * avg_s[tid % 20];
    fused[b * 200 + tid] = val;
  }
  double sv = (double)val, sq = (double)val * (double)val;
#pragma unroll
  for (int off = 32; off > 0; off >>= 1) {
    sv += __shfl_down(sv, off);
    sq += __shfl_down(sq, off);
  }
  const int wid = tid >> 6;
  if ((tid & 63) == 0) { red_s[wid * 2] = sv; red_s[wid * 2 + 1] = sq; }
  __syncthreads();
  if (tid == 0) {
    double S = 0.0, Q = 0.0;
#pragma unroll
    for (int w = 0; w < 4; ++w) { S += red_s[w * 2]; Q += red_s[w * 2 + 1]; }
    stats[b * 2] = S;
    stats[b * 2 + 1] = Q;
  }
}

// K7: reduce stats -> mean/var -> bn -> logits -> log_softmax. One block.
__global__ void __launch_bounds__(1024) k_head(const float* __restrict__ fused,
                                               const double* __restrict__ stats,
                                               const float* __restrict__ gamma,
                                               const float* __restrict__ beta,
                                               const float* __restrict__ clsw,
                                               const float* __restrict__ clsb,
                                               float* __restrict__ out) {
  __shared__ double redS[16], redQ[16];
  __shared__ float cls_s[600];
  __shared__ float cb_s[3];
  __shared__ float mr_s[2];
  const int tid = threadIdx.x;
  if (tid < 600) cls_s[tid] = clsw[tid];
  if (tid < 3) cb_s[tid] = clsb[tid];
  double s = 0.0, q = 0.0;
  if (tid < 512) { s = stats[2 * tid]; q = stats[2 * tid + 1]; }
#pragma unroll
  for (int off = 32; off > 0; off >>= 1) {
    s += __shfl_down(s, off);
    q += __shfl_down(q, off);
  }
  const int wid = tid >> 6;
  if ((tid & 63) == 0) { redS[wid] = s; redQ[wid] = q; }
  __syncthreads();
  if (tid == 0) {
    double S = 0.0, Q = 0.0;
#pragma unroll
    for (int w = 0; w < 16; ++w) { S += redS[w]; Q += redQ[w]; }
    const double mean = S / 102400.0;
    const double var = Q / 102400.0 - mean * mean;
    mr_s[0] = (float)mean;
    mr_s[1] = (float)(1.0 / sqrt(var + 1e-5));
  }
  __syncthreads();
  if (tid < 512) {
    const float mean = mr_s[0], rsig = mr_s[1];
    const float ga = gamma[0], be = beta[0];
    const float* fr = fused + tid * 200;
    float l0 = cb_s[0], l1 = cb_s[1], l2 = cb_s[2];
    for (int j = 0; j < 200; ++j) {
      const float bn = (fr[j] - mean) * rsig * ga + be;
      l0 = fmaf(bn, cls_s[j], l0);
      l1 = fmaf(bn, cls_s[200 + j], l1);
      l2 = fmaf(bn, cls_s[400 + j], l2);
    }
    const float m = fmaxf(l0, fmaxf(l1, l2));
    const float lse = m + logf(expf(l0 - m) + expf(l1 - m) + expf(l2 - m));
    out[tid * 3 + 0] = l0 - lse;
    out[tid * 3 + 1] = l1 - lse;
    out[tid * 3 + 2] = l2 - lse;
  }
}

extern "C" void kernel_launch(void* const* d_in, const int* in_sizes, int n_in,
                              void* d_out, int out_size, void* d_ws, size_t ws_size,
                              hipStream_t stream) {
  (void)in_sizes; (void)n_in; (void)out_size; (void)ws_size;
  const float* x     = (const float*)d_in[0];
  const float* wih   = (const float*)d_in[1];
  const float* whh   = (const float*)d_in[2];
  const float* bih   = (const float*)d_in[3];
  const float* bhh   = (const float*)d_in[4];
  const float* sc_w  = (const float*)d_in[5];
  const float* sc_b  = (const float*)d_in[6];
  const float* c1w   = (const float*)d_in[7];
  const float* c1b   = (const float*)d_in[8];
  const float* f1w   = (const float*)d_in[9];
  const float* f1b   = (const float*)d_in[10];
  const float* k1w   = (const float*)d_in[11];
  const float* k1b   = (const float*)d_in[12];
  const float* c2w   = (const float*)d_in[13];
  const float* c2b   = (const float*)d_in[14];
  const float* f2w   = (const float*)d_in[15];
  const float* f2b   = (const float*)d_in[16];
  const float* k2w   = (const float*)d_in[17];
  const float* k2b   = (const float*)d_in[18];
  const float* gamma = (const float*)d_in[19];
  const float* beta  = (const float*)d_in[20];
  const float* clsw  = (const float*)d_in[21];
  const float* clsb  = (const float*)d_in[22];
  float* out = (float*)d_out;
  float* ws = (float*)d_ws;

  float* pre   = ws + OFF_PRE;
  float* hseq  = ws + OFF_HSEQ;
  float* xin2  = ws + OFF_XIN2;
  float* out2  = ws + OFF_OUT2;
  float* out3  = ws + OFF_OUT3;
  float* fused = ws + OFF_FUSED;
  double* stats = (double*)(ws + OFF_STATS);

  k_pregate<<<512, 256, 0, stream>>>(x, wih, bih, bhh, pre);
  k_lstm<<<LSTM_NCH, 64, 0, stream>>>(pre, whh, hseq);
  k_hr<0, 20><<<HR_NCH, 256, 0, stream>>>(hseq, sc_w, sc_b, c1w, c1b, f1w, f1b,
                                          k1w, k1b, xin2);
  k_hr<1, 10><<<HR_NCH, 256, 0, stream>>>(xin2, nullptr, nullptr, c2w, c2b,
                                          f2w, f2b, k2w, k2b, out2);
  k_flif<<<(FB_NCH * 1000 + 255) / 256, 256, 0, stream>>>(out2, out3);
  k_fused<<<512, 256, 0, stream>>>(out3, fused, stats);
  k_head<<<1, 1024, 0, stream>>>(fused, stats, gamma, beta, clsw, clsb, out);
}

// Round 10
// 219.993 us; speedup vs baseline: 1.3133x; 1.3133x over previous
//
#include <hip/hip_runtime.h>
#include <math.h>

// ---------------------------------------------------------------------------
// HRSNN. R10: revert R9's bitmask experiment (ballot in scan loop + bfe/cvt
// decode = pure VALU regression, occupancy unmoved). Back to R8 float spike
// rows, but with the lif3 scan software-pipelined against conv60: wave 0
// scans 16-row stages into a ping-pong LDS buffer while waves 1-3 conv the
// previous stage. hl LDS 23KB -> 7.7KB, total ~40KB -> 3-4 blocks/CU and a
// single dispatch round; scan latency hides behind conv. All FP formulas and
// accumulation orders byte-identical to R8 -> absmax stays exactly 0.125.
// ---------------------------------------------------------------------------

namespace {
constexpr int TT = 51200;  // B*T
constexpr double TAU1d = 1.2231301601484298;  // exp(-1.5)+1
constexpr double TAU2d = 1.3678794411714423;  // exp(-1.0)+1  (== TAU4)
constexpr double TAU3d = 1.4493289641172216;  // exp(-0.8)+1

constexpr int LSTM_L = 32, LSTM_W = 96, LSTM_NCH = TT / LSTM_L;  // 1600
constexpr int HRL = 64;                  // hr-module output chunk length
constexpr int HR_NCH = TT / HRL;         // 800
constexpr int FB_L = 32, FB_W = 32, FB_NCH = 512 / FB_L;  // 16

// workspace layout (float offsets)
constexpr size_t OFF_PRE   = 0;         // 51200*40 (+320 over-read pad)
constexpr size_t OFF_HSEQ  = 2048320;   // 51200*10
constexpr size_t OFF_XIN2  = 3072000;   // 51200*20
constexpr size_t OFF_OUT2  = 4096000;   // 51200*10
constexpr size_t OFF_OUT3  = 4608320;   // 512*100*10
constexpr size_t OFF_FUSED = 5120320;   // 512*200
constexpr size_t OFF_STATS = 5222720;   // 512*2 doubles (8-byte aligned)
}  // namespace

__device__ __forceinline__ float rcp_nr(float d) {
  float r = __builtin_amdgcn_rcpf(d);
  return r * (2.0f - d * r);  // one Newton step: ~1ulp
}

// K1: pregate[(b*100+tt)*40+l] = sum_c x[b][c][tt]*wih[l][c] + bih[l]+bhh[l]
__global__ void __launch_bounds__(256) k_pregate(const float* __restrict__ x,
                                                 const float* __restrict__ wih,
                                                 const float* __restrict__ bih,
                                                 const float* __restrict__ bhh,
                                                 float* __restrict__ pre) {
  __shared__ __align__(16) float xs[6400];   // xs[c*100+tt]
  __shared__ __align__(16) float wT[2560];   // wT[c*40+l]
  __shared__ float bl[40];
  const int b = blockIdx.x;
  const int tid = threadIdx.x;
  for (int i = tid; i < 6400; i += 256) xs[i] = x[b * 6400 + i];  // coalesced
  for (int i = tid; i < 2560; i += 256) {
    const int c = i / 40;
    const int l = i - c * 40;
    wT[i] = wih[l * 64 + c];
  }
  if (tid < 40) bl[tid] = bih[tid] + bhh[tid];
  __syncthreads();
  if (tid >= 250) return;              // 25 tt-tiles x 10 l-tiles
  const int ttile = tid / 10;
  const int ltile = tid - ttile * 10;
  const int tt0 = ttile * 4;
  const int l0 = ltile * 4;
  float acc[4][4];
#pragma unroll
  for (int i = 0; i < 4; ++i)
#pragma unroll
    for (int j = 0; j < 4; ++j) acc[i][j] = bl[l0 + j];
#pragma unroll 8
  for (int c = 0; c < 64; ++c) {
    const float4 wv = *(const float4*)&wT[c * 40 + l0];
    const float4 xv = *(const float4*)&xs[c * 100 + tt0];
    const float xa[4] = {xv.x, xv.y, xv.z, xv.w};
    const float wa[4] = {wv.x, wv.y, wv.z, wv.w};
#pragma unroll
    for (int i = 0; i < 4; ++i)
#pragma unroll
      for (int j = 0; j < 4; ++j) acc[i][j] = fmaf(xa[i], wa[j], acc[i][j]);
  }
#pragma unroll
  for (int i = 0; i < 4; ++i) {
    float4 o;
    o.x = acc[i][0]; o.y = acc[i][1]; o.z = acc[i][2]; o.w = acc[i][3];
    *(float4*)&pre[(b * 100 + tt0 + i) * 40 + l0] = o;
  }
}

// K2: chunk-parallel LSTM (warm-up LSTM_W from (0,0) -> bit-exact merge).
__global__ void __launch_bounds__(64) k_lstm(const float* __restrict__ pre,
                                             const float* __restrict__ whh,
                                             float* __restrict__ hseq) {
  const int lane = threadIdx.x;
  const int l = lane < 40 ? lane : 0;
  float wh[10];
#pragma unroll
  for (int j = 0; j < 10; ++j) wh[j] = whh[l * 10 + j];
  const int jm = lane % 10;
  const bool is_g = (l >= 20) & (l < 30);
  const float sel = is_g ? 2.0f : -1.0f;
  const int outstart = blockIdx.x * LSTM_L;
  const int start = (outstart >= LSTM_W) ? outstart - LSTM_W : 0;  // mult of 32
  const int end = outstart + LSTM_L;
  float cst = 0.0f;
  float h[10];
#pragma unroll
  for (int j = 0; j < 10; ++j) h[j] = 0.0f;
  float pbuf[8];
#pragma unroll
  for (int i = 0; i < 8; ++i) pbuf[i] = pre[(start + i) * 40 + l];
#pragma unroll 8
  for (int t = start; t < end; ++t) {
    float g = pbuf[t & 7];
    pbuf[t & 7] = pre[(t + 8) * 40 + l];  // last chunk over-reads into pad
#pragma unroll
    for (int j = 0; j < 10; ++j) g = fmaf(h[j], wh[j], g);
    const float e = __expf(sel * g);
    const float r = rcp_nr(1.0f + e);
    const float act = is_g ? (1.0f - 2.0f * r) : r;
    const float ai = __shfl(act, jm);
    const float af = __shfl(act, jm + 10);
    const float ag = __shfl(act, jm + 20);
    const float ao = __shfl(act, jm + 30);
    cst = af * cst + ai * ag;
    const float hn = ao * (1.0f - 2.0f * rcp_nr(__expf(2.0f * cst) + 1.0f));
    if ((lane < 10) & (t >= outstart)) hseq[t * 10 + lane] = hn;
#pragma unroll
    for (int j = 0; j < 10; ++j)
      h[j] = __uint_as_float(__builtin_amdgcn_readlane(__float_as_uint(hn), j));
  }
}

// K3/K4: fused hr_module, 256 threads. lif3 scan pipelined against conv60
// in 16-row stages (ping-pong hl buffer). Float spike rows (R8 semantics).
template <int MODE, int O>
__global__ void __launch_bounds__(256) k_hr(const float* __restrict__ src,
                                            const float* __restrict__ sw,
                                            const float* __restrict__ sb,
                                            const float* __restrict__ cw,
                                            const float* __restrict__ cb,
                                            const float* __restrict__ fw,
                                            const float* __restrict__ fb,
                                            const float* __restrict__ skw,
                                            const float* __restrict__ skb,
                                            float* __restrict__ outp) {
  __shared__ __align__(16) float xin_s[128 * 20];      // 10.0 KB
  __shared__ __align__(16) float c_s[96 * 20];         // 7.5 KB (hs overlay)
  __shared__ __align__(16) float hlb_s[2][16 * 60];    // 7.5 KB ping-pong
  __shared__ __align__(16) float s4_s[HRL * 20];       // 5.0 KB
  __shared__ __align__(16) float cw_s[1200];           // 4.7 KB
  __shared__ __align__(16) float fw_s[O * 20];
  __shared__ __align__(16) float skw_s[O * 20];
  __shared__ __align__(16) float sw_s[MODE == 0 ? 200 : 4];
  __shared__ float cb_s[20];
  __shared__ float fb_s[O];
  __shared__ float skb_s[O];
  __shared__ float sb_s[20];

  const int tid = threadIdx.x;
  const int outstart = blockIdx.x * HRL;
  const int end = outstart + HRL;
  const int s2 = (outstart >= 32) ? outstart - 32 : 0;
  const int s1 = (s2 >= 32) ? s2 - 32 : 0;
  const int n1 = end - s1;  // <=128, multiple of 32
  const int n2 = end - s2;  // 64 or 96, multiple of 16

  // ---- stage weights + input (float4) ----
  for (int i = tid; i < 300; i += 256)
    ((float4*)cw_s)[i] = ((const float4*)cw)[i];
  for (int i = tid; i < O * 5; i += 256) {
    ((float4*)fw_s)[i] = ((const float4*)fw)[i];
    ((float4*)skw_s)[i] = ((const float4*)skw)[i];
  }
  if (tid < O) { fb_s[tid] = fb[tid]; skb_s[tid] = skb[tid]; }
  if (tid >= 32 && tid < 52) cb_s[tid - 32] = cb[tid - 32];
  if (MODE == 0) {
    for (int i = tid; i < 50; i += 256)
      ((float4*)sw_s)[i] = ((const float4*)sw)[i];
    if (tid >= 64 && tid < 84) sb_s[tid - 64] = sb[tid - 64];
    // hseq chunk staged into c_s (dead until conv writes it; barrier-separated)
    const float4* gsrc = (const float4*)(src + (size_t)s1 * 10);
    for (int i = tid; i < n1 * 10 / 4; i += 256) ((float4*)c_s)[i] = gsrc[i];
  } else {
    const float4* gsrc = (const float4*)(src + (size_t)s1 * 20);
    for (int i = tid; i < n1 * 5; i += 256) ((float4*)xin_s)[i] = gsrc[i];
  }
  __syncthreads();

  // ---- P1: sconv -> xin_s (MODE 0). thread=(o,rg), weights in regs ----
  if (MODE == 0) {
    const int rg = tid / 20;
    const int o = tid - rg * 20;
    if (rg < 12) {
      float2 w[5];
      const float* wp = sw_s + o * 10;
#pragma unroll
      for (int q = 0; q < 5; ++q) w[q] = *(const float2*)&wp[q * 2];
      const float bias = sb_s[o];
      for (int rel = rg; rel < n1; rel += 12) {
        const float* hp = c_s + rel * 10;  // broadcast across the 20 o-lanes
        float acc = bias;
#pragma unroll
        for (int q = 0; q < 5; ++q) {
          const float2 h = *(const float2*)&hp[q * 2];
          acc = fmaf(h.x, w[q].x, acc);
          acc = fmaf(h.y, w[q].y, acc);
        }
        xin_s[rel * 20 + o] = acc;
      }
    }
    __syncthreads();
  }

  // ---- P2/P3 pipeline: wave0 lif3-scans 16-row stages; waves 1-3 conv ----
  // lif3 per-lane params (wave 0)
  const int cid = tid < 60 ? tid : 0;
  const int fch = cid / 3;
  const int kch = cid - fch * 3;
  const float rt3 = (kch == 0) ? 1.0f / (float)TAU1d
                  : (kch == 1) ? 1.0f / (float)TAU2d : 1.0f / (float)TAU3d;
  const float th3 = (kch == 0) ? 0.14f : (kch == 1) ? 0.08f : 0.06f;
  float v3 = 0.0f;
  // conv thread mapping (waves 1-3): local<180 active, o + row-stream
  const int local = tid - 64;
  const int co = (local >= 0) ? local % 20 : 0;
  const int cst_ = (local >= 0) ? local / 20 : 9;  // stream id, <9 active
  float4 wreg[15];
  if (tid >= 64 && cst_ < 9) {
    const float* wp = cw_s + co * 60;
#pragma unroll
    for (int q = 0; q < 15; ++q) wreg[q] = *(const float4*)&wp[q * 4];
  }
  // warm-up scan [s1, s2) — no outputs
  if (tid < 64) {
    for (int t = s1; t < s2; ++t) {
      const float x = xin_s[(t - s1) * 20 + fch];
      v3 = fmaf(x - v3, rt3, v3);
      const float sp = (v3 - th3 >= 0.0f) ? 1.0f : 0.0f;
      v3 = (sp != 0.0f) ? 0.0f : v3;
    }
  }
  __syncthreads();
  const int nst = n2 >> 4;  // 4 or 6 stages of 16 rows
  for (int s = 0; s <= nst; ++s) {
    if (s < nst && tid < 64) {
      float* buf = hlb_s[s & 1];
      const int t0 = s2 + s * 16;
#pragma unroll 4
      for (int i = 0; i < 16; ++i) {
        const float x = xin_s[(t0 + i - s1) * 20 + fch];
        v3 = fmaf(x - v3, rt3, v3);
        const float sp = (v3 - th3 >= 0.0f) ? 1.0f : 0.0f;
        if (tid < 60) buf[i * 60 + tid] = sp;
        v3 = (sp != 0.0f) ? 0.0f : v3;
      }
    }
    if (s > 0 && tid >= 64 && cst_ < 9) {
      const float* buf = hlb_s[(s - 1) & 1];
      const int base = (s - 1) * 16;
      const float bias = cb_s[co];
      for (int r = cst_; r < 16; r += 9) {
        const float* hp = buf + r * 60;  // broadcast across the 20 o-lanes
        float acc = bias;
#pragma unroll
        for (int q = 0; q < 15; ++q) {
          const float4 h = *(const float4*)&hp[q * 4];
          acc = fmaf(h.x, wreg[q].x, acc);
          acc = fmaf(h.y, wreg[q].y, acc);
          acc = fmaf(h.z, wreg[q].z, acc);
          acc = fmaf(h.w, wreg[q].w, acc);
        }
        c_s[(base + r) * 20 + co] = acc;
      }
    }
    __syncthreads();
  }

  // ---- P4: lifseq scan (wave 0, 20 chains) ----
  if (tid < 64) {
    const int f = tid < 20 ? tid : 0;
    const float rt = 1.0f / (float)TAU2d;
    float v = 0.0f;
#pragma unroll 8
    for (int t = s2; t < end; ++t) {
      const float x = c_s[(t - s2) * 20 + f];
      v = fmaf(x - v, rt, v);
      const float sp = (v - 0.08f >= 0.0f) ? 1.0f : 0.0f;
      if ((tid < 20) & (t >= outstart)) s4_s[(t - outstart) * 20 + tid] = sp;
      v = (sp != 0.0f) ? 0.0f : v;
    }
  }
  __syncthreads();

  // ---- P5: fcskip -> hlb_s (dead), then coalesced global store ----
  float* res = &hlb_s[0][0];  // HRL*O <= 1280 floats <= 1920 available
  {
    constexpr int ORG = (O == 20) ? 12 : 25;
    const int rg = tid / O;
    const int o = tid - rg * O;
    const int xoff = outstart - s1;
    if (rg < ORG) {
      float4 fv[5], kv[5];
      const float* fwp = fw_s + o * 20;
      const float* swp = skw_s + o * 20;
#pragma unroll
      for (int q = 0; q < 5; ++q) {
        fv[q] = *(const float4*)&fwp[q * 4];
        kv[q] = *(const float4*)&swp[q * 4];
      }
      const float bias = fb_s[o] + skb_s[o];
      for (int rel = rg; rel < HRL; rel += ORG) {
        const float* s = s4_s + rel * 20;            // broadcast rows
        const float* xi = xin_s + (xoff + rel) * 20; // broadcast rows
        float acc = bias;
#pragma unroll
        for (int q = 0; q < 5; ++q) {
          const float4 sv = *(const float4*)&s[q * 4];
          const float4 xv = *(const float4*)&xi[q * 4];
          acc = fmaf(sv.x, fv[q].x, fmaf(xv.x, kv[q].x, acc));
          acc = fmaf(sv.y, fv[q].y, fmaf(xv.y, kv[q].y, acc));
          acc = fmaf(sv.z, fv[q].z, fmaf(xv.z, kv[q].z, acc));
          acc = fmaf(sv.w, fv[q].w, fmaf(xv.w, kv[q].w, acc));
        }
        res[rel * O + o] = acc;
      }
    }
  }
  __syncthreads();
  {
    float4* gout = (float4*)(outp + (size_t)outstart * O);
    for (int i = tid; i < HRL * O / 4; i += 256) gout[i] = ((float4*)res)[i];
  }
}

// K5: final LIF over batch axis: 1000 chains, chunked over b (L=W=32).
__global__ void __launch_bounds__(256) k_flif(const float* __restrict__ out2,
                                              float* __restrict__ out3) {
  const int idx = blockIdx.x * 256 + threadIdx.x;
  if (idx >= FB_NCH * 1000) return;
  const int chunk = idx / 1000;
  const int chain = idx - chunk * 1000;
  const float rt = 1.0f / (float)TAU2d;
  const int outstart = chunk * FB_L;
  const int start = (outstart >= FB_W) ? outstart - FB_W : 0;
  const int end = outstart + FB_L;
  float v = 0.0f;
  float xb[4];
#pragma unroll
  for (int i = 0; i < 4; ++i) xb[i] = out2[(start + i) * 1000 + chain];
#pragma unroll 4
  for (int b = start; b < end; ++b) {
    const float x = xb[b & 3];
    xb[b & 3] = out2[(b + 4) * 1000 + chain];  // over-read harmless (unused)
    v = fmaf(x - v, rt, v);
    const float sp = (v - 0.08f >= 0.0f) ? 1.0f : 0.0f;
    if (b >= outstart) out3[b * 1000 + chain] = sp;
    v = (sp != 0.0f) ? 0.0f : v;
  }
}

// K6: dp -> avg -> fused; per-block (per-b) partial sum/sumsq in double.
__global__ void __launch_bounds__(256) k_fused(const float* __restrict__ out3,
                                               float* __restrict__ fused,
                                               double* __restrict__ stats) {
  __shared__ float dp_s[200];
  __shared__ float avg_s[20];
  __shared__ double red_s[8];
  const int b = blockIdx.x;
  const int tid = threadIdx.x;
  if (tid < 200) {
    const int f = tid / 20;
    const int seg = tid - f * 20;
    const float* base = out3 + b * 1000 + seg * 50 + f;
    dp_s[tid] = ((base[30] + base[40]) - (base[0] + base[10])) * 0.5f;
  }
  __syncthreads();
  if (tid < 20) {
    float s = 0.0f;
#pragma unroll
    for (int f = 0; f < 10; ++f) s += dp_s[f * 20 + tid];
    avg_s[tid] = s / 10.0f;
  }
  __syncthreads();
  float val = 0.0f;
  if (tid < 200) {
    val = dp_s[tid] * avg_s[tid % 20];
    fused[b * 200 + tid] = val;
  }
  double sv = (double)val, sq = (double)val * (double)val;
#pragma unroll
  for (int off = 32; off > 0; off >>= 1) {
    sv += __shfl_down(sv, off);
    sq += __shfl_down(sq, off);
  }
  const int wid = tid >> 6;
  if ((tid & 63) == 0) { red_s[wid * 2] = sv; red_s[wid * 2 + 1] = sq; }
  __syncthreads();
  if (tid == 0) {
    double S = 0.0, Q = 0.0;
#pragma unroll
    for (int w = 0; w < 4; ++w) { S += red_s[w * 2]; Q += red_s[w * 2 + 1]; }
    stats[b * 2] = S;
    stats[b * 2 + 1] = Q;
  }
}

// K7: reduce stats -> mean/var -> bn -> logits -> log_softmax. One block.
__global__ void __launch_bounds__(1024) k_head(const float* __restrict__ fused,
                                               const double* __restrict__ stats,
                                               const float* __restrict__ gamma,
                                               const float* __restrict__ beta,
                                               const float* __restrict__ clsw,
                                               const float* __restrict__ clsb,
                                               float* __restrict__ out) {
  __shared__ double redS[16], redQ[16];
  __shared__ float cls_s[600];
  __shared__ float cb_s[3];
  __shared__ float mr_s[2];
  const int tid = threadIdx.x;
  if (tid < 600) cls_s[tid] = clsw[tid];
  if (tid < 3) cb_s[tid] = clsb[tid];
  double s = 0.0, q = 0.0;
  if (tid < 512) { s = stats[2 * tid]; q = stats[2 * tid + 1]; }
#pragma unroll
  for (int off = 32; off > 0; off >>= 1) {
    s += __shfl_down(s, off);
    q += __shfl_down(q, off);
  }
  const int wid = tid >> 6;
  if ((tid & 63) == 0) { redS[wid] = s; redQ[wid] = q; }
  __syncthreads();
  if (tid == 0) {
    double S = 0.0, Q = 0.0;
#pragma unroll
    for (int w = 0; w < 16; ++w) { S += redS[w]; Q += redQ[w]; }
    const double mean = S / 102400.0;
    const double var = Q / 102400.0 - mean * mean;
    mr_s[0] = (float)mean;
    mr_s[1] = (float)(1.0 / sqrt(var + 1e-5));
  }
  __syncthreads();
  if (tid < 512) {
    const float mean = mr_s[0], rsig = mr_s[1];
    const float ga = gamma[0], be = beta[0];
    const float* fr = fused + tid * 200;
    float l0 = cb_s[0], l1 = cb_s[1], l2 = cb_s[2];
    for (int j = 0; j < 200; ++j) {
      const float bn = (fr[j] - mean) * rsig * ga + be;
      l0 = fmaf(bn, cls_s[j], l0);
      l1 = fmaf(bn, cls_s[200 + j], l1);
      l2 = fmaf(bn, cls_s[400 + j], l2);
    }
    const float m = fmaxf(l0, fmaxf(l1, l2));
    const float lse = m + logf(expf(l0 - m) + expf(l1 - m) + expf(l2 - m));
    out[tid * 3 + 0] = l0 - lse;
    out[tid * 3 + 1] = l1 - lse;
    out[tid * 3 + 2] = l2 - lse;
  }
}

extern "C" void kernel_launch(void* const* d_in, const int* in_sizes, int n_in,
                              void* d_out, int out_size, void* d_ws, size_t ws_size,
                              hipStream_t stream) {
  (void)in_sizes; (void)n_in; (void)out_size; (void)ws_size;
  const float* x     = (const float*)d_in[0];
  const float* wih   = (const float*)d_in[1];
  const float* whh   = (const float*)d_in[2];
  const float* bih   = (const float*)d_in[3];
  const float* bhh   = (const float*)d_in[4];
  const float* sc_w  = (const float*)d_in[5];
  const float* sc_b  = (const float*)d_in[6];
  const float* c1w   = (const float*)d_in[7];
  const float* c1b   = (const float*)d_in[8];
  const float* f1w   = (const float*)d_in[9];
  const float* f1b   = (const float*)d_in[10];
  const float* k1w   = (const float*)d_in[11];
  const float* k1b   = (const float*)d_in[12];
  const float* c2w   = (const float*)d_in[13];
  const float* c2b   = (const float*)d_in[14];
  const float* f2w   = (const float*)d_in[15];
  const float* f2b   = (const float*)d_in[16];
  const float* k2w   = (const float*)d_in[17];
  const float* k2b   = (const float*)d_in[18];
  const float* gamma = (const float*)d_in[19];
  const float* beta  = (const float*)d_in[20];
  const float* clsw  = (const float*)d_in[21];
  const float* clsb  = (const float*)d_in[22];
  float* out = (float*)d_out;
  float* ws = (float*)d_ws;

  float* pre   = ws + OFF_PRE;
  float* hseq  = ws + OFF_HSEQ;
  float* xin2  = ws + OFF_XIN2;
  float* out2  = ws + OFF_OUT2;
  float* out3  = ws + OFF_OUT3;
  float* fused = ws + OFF_FUSED;
  double* stats = (double*)(ws + OFF_STATS);

  k_pregate<<<512, 256, 0, stream>>>(x, wih, bih, bhh, pre);
  k_lstm<<<LSTM_NCH, 64, 0, stream>>>(pre, whh, hseq);
  k_hr<0, 20><<<HR_NCH, 256, 0, stream>>>(hseq, sc_w, sc_b, c1w, c1b, f1w, f1b,
                                          k1w, k1b, xin2);
  k_hr<1, 10><<<HR_NCH, 256, 0, stream>>>(xin2, nullptr, nullptr, c2w, c2b,
                                          f2w, f2b, k2w, k2b, out2);
  k_flif<<<(FB_NCH * 1000 + 255) / 256, 256, 0, stream>>>(out2, out3);
  k_fused<<<512, 256, 0, stream>>>(out3, fused, stats);
  k_head<<<1, 1024, 0, stream>>>(fused, stats, gamma, beta, clsw, clsb, out);
}

// Round 11
// 210.570 us; speedup vs baseline: 1.3721x; 1.0448x over previous
//
#include <hip/hip_runtime.h>
#include <math.h>

// ---------------------------------------------------------------------------
// HRSNN. R11: scans batch-prefetched. R10's k_hr serial scans were LDS
// *latency* bound (dependent ds_read ~120cy per step, only 4 in flight).
// Now every scan loads 16 steps' inputs into registers (16 independent
// ds_reads, one waitcnt) then scans from regs (~20cy/step). LSTM warm-up
// 96->64 (contraction >=1 bit/step -> 64+ bits >> 28-bit merge requirement;
// R3/R4/R6 halvings all bit-exact). FP formulas and accumulation order
// unchanged everywhere -> absmax stays exactly 0.125.
// ---------------------------------------------------------------------------

namespace {
constexpr int TT = 51200;  // B*T
constexpr double TAU1d = 1.2231301601484298;  // exp(-1.5)+1
constexpr double TAU2d = 1.3678794411714423;  // exp(-1.0)+1  (== TAU4)
constexpr double TAU3d = 1.4493289641172216;  // exp(-0.8)+1

constexpr int LSTM_L = 32, LSTM_W = 64, LSTM_NCH = TT / LSTM_L;  // 1600
constexpr int HRL = 64;                  // hr-module output chunk length
constexpr int HR_NCH = TT / HRL;         // 800
constexpr int FB_L = 32, FB_W = 32, FB_NCH = 512 / FB_L;  // 16

// workspace layout (float offsets)
constexpr size_t OFF_PRE   = 0;         // 51200*40 (+320 over-read pad)
constexpr size_t OFF_HSEQ  = 2048320;   // 51200*10
constexpr size_t OFF_XIN2  = 3072000;   // 51200*20
constexpr size_t OFF_OUT2  = 4096000;   // 51200*10
constexpr size_t OFF_OUT3  = 4608320;   // 512*100*10
constexpr size_t OFF_FUSED = 5120320;   // 512*200
constexpr size_t OFF_STATS = 5222720;   // 512*2 doubles (8-byte aligned)
}  // namespace

__device__ __forceinline__ float rcp_nr(float d) {
  float r = __builtin_amdgcn_rcpf(d);
  return r * (2.0f - d * r);  // one Newton step: ~1ulp
}

// K1: pregate[(b*100+tt)*40+l] = sum_c x[b][c][tt]*wih[l][c] + bih[l]+bhh[l]
__global__ void __launch_bounds__(256) k_pregate(const float* __restrict__ x,
                                                 const float* __restrict__ wih,
                                                 const float* __restrict__ bih,
                                                 const float* __restrict__ bhh,
                                                 float* __restrict__ pre) {
  __shared__ __align__(16) float xs[6400];   // xs[c*100+tt]
  __shared__ __align__(16) float wT[2560];   // wT[c*40+l]
  __shared__ float bl[40];
  const int b = blockIdx.x;
  const int tid = threadIdx.x;
  for (int i = tid; i < 6400; i += 256) xs[i] = x[b * 6400 + i];  // coalesced
  for (int i = tid; i < 2560; i += 256) {
    const int c = i / 40;
    const int l = i - c * 40;
    wT[i] = wih[l * 64 + c];
  }
  if (tid < 40) bl[tid] = bih[tid] + bhh[tid];
  __syncthreads();
  if (tid >= 250) return;              // 25 tt-tiles x 10 l-tiles
  const int ttile = tid / 10;
  const int ltile = tid - ttile * 10;
  const int tt0 = ttile * 4;
  const int l0 = ltile * 4;
  float acc[4][4];
#pragma unroll
  for (int i = 0; i < 4; ++i)
#pragma unroll
    for (int j = 0; j < 4; ++j) acc[i][j] = bl[l0 + j];
#pragma unroll 8
  for (int c = 0; c < 64; ++c) {
    const float4 wv = *(const float4*)&wT[c * 40 + l0];
    const float4 xv = *(const float4*)&xs[c * 100 + tt0];
    const float xa[4] = {xv.x, xv.y, xv.z, xv.w};
    const float wa[4] = {wv.x, wv.y, wv.z, wv.w};
#pragma unroll
    for (int i = 0; i < 4; ++i)
#pragma unroll
      for (int j = 0; j < 4; ++j) acc[i][j] = fmaf(xa[i], wa[j], acc[i][j]);
  }
#pragma unroll
  for (int i = 0; i < 4; ++i) {
    float4 o;
    o.x = acc[i][0]; o.y = acc[i][1]; o.z = acc[i][2]; o.w = acc[i][3];
    *(float4*)&pre[(b * 100 + tt0 + i) * 40 + l0] = o;
  }
}

// K2: chunk-parallel LSTM (warm-up LSTM_W from (0,0) -> bit-exact merge).
__global__ void __launch_bounds__(64) k_lstm(const float* __restrict__ pre,
                                             const float* __restrict__ whh,
                                             float* __restrict__ hseq) {
  const int lane = threadIdx.x;
  const int l = lane < 40 ? lane : 0;
  float wh[10];
#pragma unroll
  for (int j = 0; j < 10; ++j) wh[j] = whh[l * 10 + j];
  const int jm = lane % 10;
  const bool is_g = (l >= 20) & (l < 30);
  const float sel = is_g ? 2.0f : -1.0f;
  const int outstart = blockIdx.x * LSTM_L;
  const int start = (outstart >= LSTM_W) ? outstart - LSTM_W : 0;  // mult of 32
  const int end = outstart + LSTM_L;
  float cst = 0.0f;
  float h[10];
#pragma unroll
  for (int j = 0; j < 10; ++j) h[j] = 0.0f;
  float pbuf[8];
#pragma unroll
  for (int i = 0; i < 8; ++i) pbuf[i] = pre[(start + i) * 40 + l];
#pragma unroll 8
  for (int t = start; t < end; ++t) {
    float g = pbuf[t & 7];
    pbuf[t & 7] = pre[(t + 8) * 40 + l];  // last chunk over-reads into pad
#pragma unroll
    for (int j = 0; j < 10; ++j) g = fmaf(h[j], wh[j], g);
    const float e = __expf(sel * g);
    const float r = rcp_nr(1.0f + e);
    const float act = is_g ? (1.0f - 2.0f * r) : r;
    const float ai = __shfl(act, jm);
    const float af = __shfl(act, jm + 10);
    const float ag = __shfl(act, jm + 20);
    const float ao = __shfl(act, jm + 30);
    cst = af * cst + ai * ag;
    const float hn = ao * (1.0f - 2.0f * rcp_nr(__expf(2.0f * cst) + 1.0f));
    if ((lane < 10) & (t >= outstart)) hseq[t * 10 + lane] = hn;
#pragma unroll
    for (int j = 0; j < 10; ++j)
      h[j] = __uint_as_float(__builtin_amdgcn_readlane(__float_as_uint(hn), j));
  }
}

// K3/K4: fused hr_module, 256 threads. lif3 scan pipelined against conv60
// in 16-row stages; ALL scans batch-prefetch 16 inputs into registers.
template <int MODE, int O>
__global__ void __launch_bounds__(256) k_hr(const float* __restrict__ src,
                                            const float* __restrict__ sw,
                                            const float* __restrict__ sb,
                                            const float* __restrict__ cw,
                                            const float* __restrict__ cb,
                                            const float* __restrict__ fw,
                                            const float* __restrict__ fb,
                                            const float* __restrict__ skw,
                                            const float* __restrict__ skb,
                                            float* __restrict__ outp) {
  __shared__ __align__(16) float xin_s[128 * 20];      // 10.0 KB
  __shared__ __align__(16) float c_s[96 * 20];         // 7.5 KB (hs overlay)
  __shared__ __align__(16) float hlb_s[2][16 * 60];    // 7.5 KB ping-pong
  __shared__ __align__(16) float s4_s[HRL * 20];       // 5.0 KB
  __shared__ __align__(16) float cw_s[1200];           // 4.7 KB
  __shared__ __align__(16) float fw_s[O * 20];
  __shared__ __align__(16) float skw_s[O * 20];
  __shared__ __align__(16) float sw_s[MODE == 0 ? 200 : 4];
  __shared__ float cb_s[20];
  __shared__ float fb_s[O];
  __shared__ float skb_s[O];
  __shared__ float sb_s[20];

  const int tid = threadIdx.x;
  const int outstart = blockIdx.x * HRL;
  const int end = outstart + HRL;
  const int s2 = (outstart >= 32) ? outstart - 32 : 0;
  const int s1 = (s2 >= 32) ? s2 - 32 : 0;
  const int n1 = end - s1;  // <=128, multiple of 32
  const int n2 = end - s2;  // 64 or 96, multiple of 16

  // ---- stage weights + input (float4) ----
  for (int i = tid; i < 300; i += 256)
    ((float4*)cw_s)[i] = ((const float4*)cw)[i];
  for (int i = tid; i < O * 5; i += 256) {
    ((float4*)fw_s)[i] = ((const float4*)fw)[i];
    ((float4*)skw_s)[i] = ((const float4*)skw)[i];
  }
  if (tid < O) { fb_s[tid] = fb[tid]; skb_s[tid] = skb[tid]; }
  if (tid >= 32 && tid < 52) cb_s[tid - 32] = cb[tid - 32];
  if (MODE == 0) {
    for (int i = tid; i < 50; i += 256)
      ((float4*)sw_s)[i] = ((const float4*)sw)[i];
    if (tid >= 64 && tid < 84) sb_s[tid - 64] = sb[tid - 64];
    // hseq chunk staged into c_s (dead until conv writes it; barrier-separated)
    const float4* gsrc = (const float4*)(src + (size_t)s1 * 10);
    for (int i = tid; i < n1 * 10 / 4; i += 256) ((float4*)c_s)[i] = gsrc[i];
  } else {
    const float4* gsrc = (const float4*)(src + (size_t)s1 * 20);
    for (int i = tid; i < n1 * 5; i += 256) ((float4*)xin_s)[i] = gsrc[i];
  }
  __syncthreads();

  // ---- P1: sconv -> xin_s (MODE 0). thread=(o,rg), weights in regs ----
  if (MODE == 0) {
    const int rg = tid / 20;
    const int o = tid - rg * 20;
    if (rg < 12) {
      float2 w[5];
      const float* wp = sw_s + o * 10;
#pragma unroll
      for (int q = 0; q < 5; ++q) w[q] = *(const float2*)&wp[q * 2];
      const float bias = sb_s[o];
      for (int rel = rg; rel < n1; rel += 12) {
        const float* hp = c_s + rel * 10;  // broadcast across the 20 o-lanes
        float acc = bias;
#pragma unroll
        for (int q = 0; q < 5; ++q) {
          const float2 h = *(const float2*)&hp[q * 2];
          acc = fmaf(h.x, w[q].x, acc);
          acc = fmaf(h.y, w[q].y, acc);
        }
        xin_s[rel * 20 + o] = acc;
      }
    }
    __syncthreads();
  }

  // ---- P2/P3 pipeline: wave0 lif3-scans 16-row stages; waves 1-3 conv ----
  const int cid = tid < 60 ? tid : 0;
  const int fch = cid / 3;
  const int kch = cid - fch * 3;
  const float rt3 = (kch == 0) ? 1.0f / (float)TAU1d
                  : (kch == 1) ? 1.0f / (float)TAU2d : 1.0f / (float)TAU3d;
  const float th3 = (kch == 0) ? 0.14f : (kch == 1) ? 0.08f : 0.06f;
  float v3 = 0.0f;
  const int local = tid - 64;
  const int co = (local >= 0) ? local % 20 : 0;
  const int cst_ = (local >= 0) ? local / 20 : 9;  // stream id, <9 active
  float4 wreg[15];
  if (tid >= 64 && cst_ < 9) {
    const float* wp = cw_s + co * 60;
#pragma unroll
    for (int q = 0; q < 15; ++q) wreg[q] = *(const float4*)&wp[q * 4];
  }
  // warm-up scan [s1, s2) — batch-prefetch 16 steps into regs, no outputs
  if (tid < 64) {
    for (int t0 = s1; t0 < s2; t0 += 16) {
      float xr[16];
#pragma unroll
      for (int i = 0; i < 16; ++i) xr[i] = xin_s[(t0 + i - s1) * 20 + fch];
#pragma unroll
      for (int i = 0; i < 16; ++i) {
        v3 = fmaf(xr[i] - v3, rt3, v3);
        const float sp = (v3 - th3 >= 0.0f) ? 1.0f : 0.0f;
        v3 = (sp != 0.0f) ? 0.0f : v3;
      }
    }
  }
  __syncthreads();
  const int nst = n2 >> 4;  // 4 or 6 stages of 16 rows
  for (int s = 0; s <= nst; ++s) {
    if (s < nst && tid < 64) {
      float* buf = hlb_s[s & 1];
      const int t0 = s2 + s * 16;
      float xr[16];
#pragma unroll
      for (int i = 0; i < 16; ++i) xr[i] = xin_s[(t0 + i - s1) * 20 + fch];
#pragma unroll
      for (int i = 0; i < 16; ++i) {
        v3 = fmaf(xr[i] - v3, rt3, v3);
        const float sp = (v3 - th3 >= 0.0f) ? 1.0f : 0.0f;
        if (tid < 60) buf[i * 60 + tid] = sp;
        v3 = (sp != 0.0f) ? 0.0f : v3;
      }
    }
    if (s > 0 && tid >= 64 && cst_ < 9) {
      const float* buf = hlb_s[(s - 1) & 1];
      const int base = (s - 1) * 16;
      const float bias = cb_s[co];
      for (int r = cst_; r < 16; r += 9) {
        const float* hp = buf + r * 60;  // broadcast across the 20 o-lanes
        float acc = bias;
#pragma unroll
        for (int q = 0; q < 15; ++q) {
          const float4 h = *(const float4*)&hp[q * 4];
          acc = fmaf(h.x, wreg[q].x, acc);
          acc = fmaf(h.y, wreg[q].y, acc);
          acc = fmaf(h.z, wreg[q].z, acc);
          acc = fmaf(h.w, wreg[q].w, acc);
        }
        c_s[(base + r) * 20 + co] = acc;
      }
    }
    __syncthreads();
  }

  // ---- P4: lifseq scan (wave 0, 20 chains), 16-step register batches ----
  if (tid < 64) {
    const int f = tid < 20 ? tid : 0;
    const float rt = 1.0f / (float)TAU2d;
    float v = 0.0f;
    for (int t0 = s2; t0 < end; t0 += 16) {
      float xr[16];
#pragma unroll
      for (int i = 0; i < 16; ++i) xr[i] = c_s[(t0 + i - s2) * 20 + f];
#pragma unroll
      for (int i = 0; i < 16; ++i) {
        v = fmaf(xr[i] - v, rt, v);
        const float sp = (v - 0.08f >= 0.0f) ? 1.0f : 0.0f;
        if ((tid < 20) & (t0 + i >= outstart))
          s4_s[(t0 + i - outstart) * 20 + tid] = sp;
        v = (sp != 0.0f) ? 0.0f : v;
      }
    }
  }
  __syncthreads();

  // ---- P5: fcskip -> hlb_s (dead), then coalesced global store ----
  float* res = &hlb_s[0][0];  // HRL*O <= 1280 floats <= 1920 available
  {
    constexpr int ORG = (O == 20) ? 12 : 25;
    const int rg = tid / O;
    const int o = tid - rg * O;
    const int xoff = outstart - s1;
    if (rg < ORG) {
      float4 fv[5], kv[5];
      const float* fwp = fw_s + o * 20;
      const float* swp = skw_s + o * 20;
#pragma unroll
      for (int q = 0; q < 5; ++q) {
        fv[q] = *(const float4*)&fwp[q * 4];
        kv[q] = *(const float4*)&swp[q * 4];
      }
      const float bias = fb_s[o] + skb_s[o];
      for (int rel = rg; rel < HRL; rel += ORG) {
        const float* s = s4_s + rel * 20;            // broadcast rows
        const float* xi = xin_s + (xoff + rel) * 20; // broadcast rows
        float acc = bias;
#pragma unroll
        for (int q = 0; q < 5; ++q) {
          const float4 sv = *(const float4*)&s[q * 4];
          const float4 xv = *(const float4*)&xi[q * 4];
          acc = fmaf(sv.x, fv[q].x, fmaf(xv.x, kv[q].x, acc));
          acc = fmaf(sv.y, fv[q].y, fmaf(xv.y, kv[q].y, acc));
          acc = fmaf(sv.z, fv[q].z, fmaf(xv.z, kv[q].z, acc));
          acc = fmaf(sv.w, fv[q].w, fmaf(xv.w, kv[q].w, acc));
        }
        res[rel * O + o] = acc;
      }
    }
  }
  __syncthreads();
  {
    float4* gout = (float4*)(outp + (size_t)outstart * O);
    for (int i = tid; i < HRL * O / 4; i += 256) gout[i] = ((float4*)res)[i];
  }
}

// K5: final LIF over batch axis: 1000 chains, chunked over b (L=W=32).
__global__ void __launch_bounds__(256) k_flif(const float* __restrict__ out2,
                                              float* __restrict__ out3) {
  const int idx = blockIdx.x * 256 + threadIdx.x;
  if (idx >= FB_NCH * 1000) return;
  const int chunk = idx / 1000;
  const int chain = idx - chunk * 1000;
  const float rt = 1.0f / (float)TAU2d;
  const int outstart = chunk * FB_L;
  const int start = (outstart >= FB_W) ? outstart - FB_W : 0;
  const int end = outstart + FB_L;
  float v = 0.0f;
  float xb[4];
#pragma unroll
  for (int i = 0; i < 4; ++i) xb[i] = out2[(start + i) * 1000 + chain];
#pragma unroll 4
  for (int b = start; b < end; ++b) {
    const float x = xb[b & 3];
    xb[b & 3] = out2[(b + 4) * 1000 + chain];  // over-read harmless (unused)
    v = fmaf(x - v, rt, v);
    const float sp = (v - 0.08f >= 0.0f) ? 1.0f : 0.0f;
    if (b >= outstart) out3[b * 1000 + chain] = sp;
    v = (sp != 0.0f) ? 0.0f : v;
  }
}

// K6: dp -> avg -> fused; per-block (per-b) partial sum/sumsq in double.
__global__ void __launch_bounds__(256) k_fused(const float* __restrict__ out3,
                                               float* __restrict__ fused,
                                               double* __restrict__ stats) {
  __shared__ float dp_s[200];
  __shared__ float avg_s[20];
  __shared__ double red_s[8];
  const int b = blockIdx.x;
  const int tid = threadIdx.x;
  if (tid < 200) {
    const int f = tid / 20;
    const int seg = tid - f * 20;
    const float* base = out3 + b * 1000 + seg * 50 + f;
    dp_s[tid] = ((base[30] + base[40]) - (base[0] + base[10])) * 0.5f;
  }
  __syncthreads();
  if (tid < 20) {
    float s = 0.0f;
#pragma unroll
    for (int f = 0; f < 10; ++f) s += dp_s[f * 20 + tid];
    avg_s[tid] = s / 10.0f;
  }
  __syncthreads();
  float val = 0.0f;
  if (tid < 200) {
    val = dp_s[tid] * avg_s[tid % 20];
    fused[b * 200 + tid] = val;
  }
  double sv = (double)val, sq = (double)val * (double)val;
#pragma unroll
  for (int off = 32; off > 0; off >>= 1) {
    sv += __shfl_down(sv, off);
    sq += __shfl_down(sq, off);
  }
  const int wid = tid >> 6;
  if ((tid & 63) == 0) { red_s[wid * 2] = sv; red_s[wid * 2 + 1] = sq; }
  __syncthreads();
  if (tid == 0) {
    double S = 0.0, Q = 0.0;
#pragma unroll
    for (int w = 0; w < 4; ++w) { S += red_s[w * 2]; Q += red_s[w * 2 + 1]; }
    stats[b * 2] = S;
    stats[b * 2 + 1] = Q;
  }
}

// K7: reduce stats -> mean/var -> bn -> logits -> log_softmax. One block.
__global__ void __launch_bounds__(1024) k_head(const float* __restrict__ fused,
                                               const double* __restrict__ stats,
                                               const float* __restrict__ gamma,
                                               const float* __restrict__ beta,
                                               const float* __restrict__ clsw,
                                               const float* __restrict__ clsb,
                                               float* __restrict__ out) {
  __shared__ double redS[16], redQ[16];
  __shared__ float cls_s[600];
  __shared__ float cb_s[3];
  __shared__ float mr_s[2];
  const int tid = threadIdx.x;
  if (tid < 600) cls_s[tid] = clsw[tid];
  if (tid < 3) cb_s[tid] = clsb[tid];
  double s = 0.0, q = 0.0;
  if (tid < 512) { s = stats[2 * tid]; q = stats[2 * tid + 1]; }
#pragma unroll
  for (int off = 32; off > 0; off >>= 1) {
    s += __shfl_down(s, off);
    q += __shfl_down(q, off);
  }
  const int wid = tid >> 6;
  if ((tid & 63) == 0) { redS[wid] = s; redQ[wid] = q; }
  __syncthreads();
  if (tid == 0) {
    double S = 0.0, Q = 0.0;
#pragma unroll
    for (int w = 0; w < 16; ++w) { S += redS[w]; Q += redQ[w]; }
    const double mean = S / 102400.0;
    const double var = Q / 102400.0 - mean * mean;
    mr_s[0] = (float)mean;
    mr_s[1] = (float)(1.0 / sqrt(var + 1e-5));
  }
  __syncthreads();
  if (tid < 512) {
    const float mean = mr_s[0], rsig = mr_s[1];
    const float ga = gamma[0], be = beta[0];
    const float* fr = fused + tid * 200;
    float l0 = cb_s[0], l1 = cb_s[1], l2 = cb_s[2];
    for (int j = 0; j < 200; ++j) {
      const float bn = (fr[j] - mean) * rsig * ga + be;
      l0 = fmaf(bn, cls_s[j], l0);
      l1 = fmaf(bn, cls_s[200 + j], l1);
      l2 = fmaf(bn, cls_s[400 + j], l2);
    }
    const float m = fmaxf(l0, fmaxf(l1, l2));
    const float lse = m + logf(expf(l0 - m) + expf(l1 - m) + expf(l2 - m));
    out[tid * 3 + 0] = l0 - lse;
    out[tid * 3 + 1] = l1 - lse;
    out[tid * 3 + 2] = l2 - lse;
  }
}

extern "C" void kernel_launch(void* const* d_in, const int* in_sizes, int n_in,
                              void* d_out, int out_size, void* d_ws, size_t ws_size,
                              hipStream_t stream) {
  (void)in_sizes; (void)n_in; (void)out_size; (void)ws_size;
  const float* x     = (const float*)d_in[0];
  const float* wih   = (const float*)d_in[1];
  const float* whh   = (const float*)d_in[2];
  const float* bih   = (const float*)d_in[3];
  const float* bhh   = (const float*)d_in[4];
  const float* sc_w  = (const float*)d_in[5];
  const float* sc_b  = (const float*)d_in[6];
  const float* c1w   = (const float*)d_in[7];
  const float* c1b   = (const float*)d_in[8];
  const float* f1w   = (const float*)d_in[9];
  const float* f1b   = (const float*)d_in[10];
  const float* k1w   = (const float*)d_in[11];
  const float* k1b   = (const float*)d_in[12];
  const float* c2w   = (const float*)d_in[13];
  const float* c2b   = (const float*)d_in[14];
  const float* f2w   = (const float*)d_in[15];
  const float* f2b   = (const float*)d_in[16];
  const float* k2w   = (const float*)d_in[17];
  const float* k2b   = (const float*)d_in[18];
  const float* gamma = (const float*)d_in[19];
  const float* beta  = (const float*)d_in[20];
  const float* clsw  = (const float*)d_in[21];
  const float* clsb  = (const float*)d_in[22];
  float* out = (float*)d_out;
  float* ws = (float*)d_ws;

  float* pre   = ws + OFF_PRE;
  float* hseq  = ws + OFF_HSEQ;
  float* xin2  = ws + OFF_XIN2;
  float* out2  = ws + OFF_OUT2;
  float* out3  = ws + OFF_OUT3;
  float* fused = ws + OFF_FUSED;
  double* stats = (double*)(ws + OFF_STATS);

  k_pregate<<<512, 256, 0, stream>>>(x, wih, bih, bhh, pre);
  k_lstm<<<LSTM_NCH, 64, 0, stream>>>(pre, whh, hseq);
  k_hr<0, 20><<<HR_NCH, 256, 0, stream>>>(hseq, sc_w, sc_b, c1w, c1b, f1w, f1b,
                                          k1w, k1b, xin2);
  k_hr<1, 10><<<HR_NCH, 256, 0, stream>>>(xin2, nullptr, nullptr, c2w, c2b,
                                          f2w, f2b, k2w, k2b, out2);
  k_flif<<<(FB_NCH * 1000 + 255) / 256, 256, 0, stream>>>(out2, out3);
  k_fused<<<512, 256, 0, stream>>>(out3, fused, stats);
  k_head<<<1, 1024, 0, stream>>>(fused, stats, gamma, beta, clsw, clsb, out);
}

// Round 12
// 196.311 us; speedup vs baseline: 1.4718x; 1.0726x over previous
//
#include <hip/hip_runtime.h>
#include <math.h>

// ---------------------------------------------------------------------------
// HRSNN. R12: k_head de-serialized. The old k_head was ONE 1024-thread block
// on ONE CU: 200 scalar scattered global loads/wave (64 lines each) + 600
// scalar ds_read/wave x 16 waves ~ tens of us serialized on a single CU's
// L1/LDS pipes. Now 8 blocks x 512 thr: each block redundantly reduces the
// 512 per-b stats (identical shuffle order; old waves 8-15 contributed exact
// +0.0 -> bit-identical mean/var), then 64 logits rows/block, one thread per
// row, float4 loads (4 sequential FMAs preserve j-ascending accumulation ->
// bit-identical logits). Everything else unchanged. absmax stays 0.125.
// ---------------------------------------------------------------------------

namespace {
constexpr int TT = 51200;  // B*T
constexpr double TAU1d = 1.2231301601484298;  // exp(-1.5)+1
constexpr double TAU2d = 1.3678794411714423;  // exp(-1.0)+1  (== TAU4)
constexpr double TAU3d = 1.4493289641172216;  // exp(-0.8)+1

constexpr int LSTM_L = 32, LSTM_W = 64, LSTM_NCH = TT / LSTM_L;  // 1600
constexpr int HRL = 64;                  // hr-module output chunk length
constexpr int HR_NCH = TT / HRL;         // 800
constexpr int FB_L = 32, FB_W = 32, FB_NCH = 512 / FB_L;  // 16

// workspace layout (float offsets)
constexpr size_t OFF_PRE   = 0;         // 51200*40 (+320 over-read pad)
constexpr size_t OFF_HSEQ  = 2048320;   // 51200*10
constexpr size_t OFF_XIN2  = 3072000;   // 51200*20
constexpr size_t OFF_OUT2  = 4096000;   // 51200*10
constexpr size_t OFF_OUT3  = 4608320;   // 512*100*10
constexpr size_t OFF_FUSED = 5120320;   // 512*200
constexpr size_t OFF_STATS = 5222720;   // 512*2 doubles (8-byte aligned)
}  // namespace

__device__ __forceinline__ float rcp_nr(float d) {
  float r = __builtin_amdgcn_rcpf(d);
  return r * (2.0f - d * r);  // one Newton step: ~1ulp
}

// K1: pregate[(b*100+tt)*40+l] = sum_c x[b][c][tt]*wih[l][c] + bih[l]+bhh[l]
__global__ void __launch_bounds__(256) k_pregate(const float* __restrict__ x,
                                                 const float* __restrict__ wih,
                                                 const float* __restrict__ bih,
                                                 const float* __restrict__ bhh,
                                                 float* __restrict__ pre) {
  __shared__ __align__(16) float xs[6400];   // xs[c*100+tt]
  __shared__ __align__(16) float wT[2560];   // wT[c*40+l]
  __shared__ float bl[40];
  const int b = blockIdx.x;
  const int tid = threadIdx.x;
  for (int i = tid; i < 6400; i += 256) xs[i] = x[b * 6400 + i];  // coalesced
  for (int i = tid; i < 2560; i += 256) {
    const int c = i / 40;
    const int l = i - c * 40;
    wT[i] = wih[l * 64 + c];
  }
  if (tid < 40) bl[tid] = bih[tid] + bhh[tid];
  __syncthreads();
  if (tid >= 250) return;              // 25 tt-tiles x 10 l-tiles
  const int ttile = tid / 10;
  const int ltile = tid - ttile * 10;
  const int tt0 = ttile * 4;
  const int l0 = ltile * 4;
  float acc[4][4];
#pragma unroll
  for (int i = 0; i < 4; ++i)
#pragma unroll
    for (int j = 0; j < 4; ++j) acc[i][j] = bl[l0 + j];
#pragma unroll 8
  for (int c = 0; c < 64; ++c) {
    const float4 wv = *(const float4*)&wT[c * 40 + l0];
    const float4 xv = *(const float4*)&xs[c * 100 + tt0];
    const float xa[4] = {xv.x, xv.y, xv.z, xv.w};
    const float wa[4] = {wv.x, wv.y, wv.z, wv.w};
#pragma unroll
    for (int i = 0; i < 4; ++i)
#pragma unroll
      for (int j = 0; j < 4; ++j) acc[i][j] = fmaf(xa[i], wa[j], acc[i][j]);
  }
#pragma unroll
  for (int i = 0; i < 4; ++i) {
    float4 o;
    o.x = acc[i][0]; o.y = acc[i][1]; o.z = acc[i][2]; o.w = acc[i][3];
    *(float4*)&pre[(b * 100 + tt0 + i) * 40 + l0] = o;
  }
}

// K2: chunk-parallel LSTM (warm-up LSTM_W from (0,0) -> bit-exact merge).
__global__ void __launch_bounds__(64) k_lstm(const float* __restrict__ pre,
                                             const float* __restrict__ whh,
                                             float* __restrict__ hseq) {
  const int lane = threadIdx.x;
  const int l = lane < 40 ? lane : 0;
  float wh[10];
#pragma unroll
  for (int j = 0; j < 10; ++j) wh[j] = whh[l * 10 + j];
  const int jm = lane % 10;
  const bool is_g = (l >= 20) & (l < 30);
  const float sel = is_g ? 2.0f : -1.0f;
  const int outstart = blockIdx.x * LSTM_L;
  const int start = (outstart >= LSTM_W) ? outstart - LSTM_W : 0;  // mult of 32
  const int end = outstart + LSTM_L;
  float cst = 0.0f;
  float h[10];
#pragma unroll
  for (int j = 0; j < 10; ++j) h[j] = 0.0f;
  float pbuf[8];
#pragma unroll
  for (int i = 0; i < 8; ++i) pbuf[i] = pre[(start + i) * 40 + l];
#pragma unroll 8
  for (int t = start; t < end; ++t) {
    float g = pbuf[t & 7];
    pbuf[t & 7] = pre[(t + 8) * 40 + l];  // last chunk over-reads into pad
#pragma unroll
    for (int j = 0; j < 10; ++j) g = fmaf(h[j], wh[j], g);
    const float e = __expf(sel * g);
    const float r = rcp_nr(1.0f + e);
    const float act = is_g ? (1.0f - 2.0f * r) : r;
    const float ai = __shfl(act, jm);
    const float af = __shfl(act, jm + 10);
    const float ag = __shfl(act, jm + 20);
    const float ao = __shfl(act, jm + 30);
    cst = af * cst + ai * ag;
    const float hn = ao * (1.0f - 2.0f * rcp_nr(__expf(2.0f * cst) + 1.0f));
    if ((lane < 10) & (t >= outstart)) hseq[t * 10 + lane] = hn;
#pragma unroll
    for (int j = 0; j < 10; ++j)
      h[j] = __uint_as_float(__builtin_amdgcn_readlane(__float_as_uint(hn), j));
  }
}

// K3/K4: fused hr_module, 256 threads. lif3 scan pipelined against conv60
// in 16-row stages; ALL scans batch-prefetch 16 inputs into registers.
template <int MODE, int O>
__global__ void __launch_bounds__(256) k_hr(const float* __restrict__ src,
                                            const float* __restrict__ sw,
                                            const float* __restrict__ sb,
                                            const float* __restrict__ cw,
                                            const float* __restrict__ cb,
                                            const float* __restrict__ fw,
                                            const float* __restrict__ fb,
                                            const float* __restrict__ skw,
                                            const float* __restrict__ skb,
                                            float* __restrict__ outp) {
  __shared__ __align__(16) float xin_s[128 * 20];      // 10.0 KB
  __shared__ __align__(16) float c_s[96 * 20];         // 7.5 KB (hs overlay)
  __shared__ __align__(16) float hlb_s[2][16 * 60];    // 7.5 KB ping-pong
  __shared__ __align__(16) float s4_s[HRL * 20];       // 5.0 KB
  __shared__ __align__(16) float cw_s[1200];           // 4.7 KB
  __shared__ __align__(16) float fw_s[O * 20];
  __shared__ __align__(16) float skw_s[O * 20];
  __shared__ __align__(16) float sw_s[MODE == 0 ? 200 : 4];
  __shared__ float cb_s[20];
  __shared__ float fb_s[O];
  __shared__ float skb_s[O];
  __shared__ float sb_s[20];

  const int tid = threadIdx.x;
  const int outstart = blockIdx.x * HRL;
  const int end = outstart + HRL;
  const int s2 = (outstart >= 32) ? outstart - 32 : 0;
  const int s1 = (s2 >= 32) ? s2 - 32 : 0;
  const int n1 = end - s1;  // <=128, multiple of 32
  const int n2 = end - s2;  // 64 or 96, multiple of 16

  // ---- stage weights + input (float4) ----
  for (int i = tid; i < 300; i += 256)
    ((float4*)cw_s)[i] = ((const float4*)cw)[i];
  for (int i = tid; i < O * 5; i += 256) {
    ((float4*)fw_s)[i] = ((const float4*)fw)[i];
    ((float4*)skw_s)[i] = ((const float4*)skw)[i];
  }
  if (tid < O) { fb_s[tid] = fb[tid]; skb_s[tid] = skb[tid]; }
  if (tid >= 32 && tid < 52) cb_s[tid - 32] = cb[tid - 32];
  if (MODE == 0) {
    for (int i = tid; i < 50; i += 256)
      ((float4*)sw_s)[i] = ((const float4*)sw)[i];
    if (tid >= 64 && tid < 84) sb_s[tid - 64] = sb[tid - 64];
    // hseq chunk staged into c_s (dead until conv writes it; barrier-separated)
    const float4* gsrc = (const float4*)(src + (size_t)s1 * 10);
    for (int i = tid; i < n1 * 10 / 4; i += 256) ((float4*)c_s)[i] = gsrc[i];
  } else {
    const float4* gsrc = (const float4*)(src + (size_t)s1 * 20);
    for (int i = tid; i < n1 * 5; i += 256) ((float4*)xin_s)[i] = gsrc[i];
  }
  __syncthreads();

  // ---- P1: sconv -> xin_s (MODE 0). thread=(o,rg), weights in regs ----
  if (MODE == 0) {
    const int rg = tid / 20;
    const int o = tid - rg * 20;
    if (rg < 12) {
      float2 w[5];
      const float* wp = sw_s + o * 10;
#pragma unroll
      for (int q = 0; q < 5; ++q) w[q] = *(const float2*)&wp[q * 2];
      const float bias = sb_s[o];
      for (int rel = rg; rel < n1; rel += 12) {
        const float* hp = c_s + rel * 10;  // broadcast across the 20 o-lanes
        float acc = bias;
#pragma unroll
        for (int q = 0; q < 5; ++q) {
          const float2 h = *(const float2*)&hp[q * 2];
          acc = fmaf(h.x, w[q].x, acc);
          acc = fmaf(h.y, w[q].y, acc);
        }
        xin_s[rel * 20 + o] = acc;
      }
    }
    __syncthreads();
  }

  // ---- P2/P3 pipeline: wave0 lif3-scans 16-row stages; waves 1-3 conv ----
  const int cid = tid < 60 ? tid : 0;
  const int fch = cid / 3;
  const int kch = cid - fch * 3;
  const float rt3 = (kch == 0) ? 1.0f / (float)TAU1d
                  : (kch == 1) ? 1.0f / (float)TAU2d : 1.0f / (float)TAU3d;
  const float th3 = (kch == 0) ? 0.14f : (kch == 1) ? 0.08f : 0.06f;
  float v3 = 0.0f;
  const int local = tid - 64;
  const int co = (local >= 0) ? local % 20 : 0;
  const int cst_ = (local >= 0) ? local / 20 : 9;  // stream id, <9 active
  float4 wreg[15];
  if (tid >= 64 && cst_ < 9) {
    const float* wp = cw_s + co * 60;
#pragma unroll
    for (int q = 0; q < 15; ++q) wreg[q] = *(const float4*)&wp[q * 4];
  }
  // warm-up scan [s1, s2) — batch-prefetch 16 steps into regs, no outputs
  if (tid < 64) {
    for (int t0 = s1; t0 < s2; t0 += 16) {
      float xr[16];
#pragma unroll
      for (int i = 0; i < 16; ++i) xr[i] = xin_s[(t0 + i - s1) * 20 + fch];
#pragma unroll
      for (int i = 0; i < 16; ++i) {
        v3 = fmaf(xr[i] - v3, rt3, v3);
        const float sp = (v3 - th3 >= 0.0f) ? 1.0f : 0.0f;
        v3 = (sp != 0.0f) ? 0.0f : v3;
      }
    }
  }
  __syncthreads();
  const int nst = n2 >> 4;  // 4 or 6 stages of 16 rows
  for (int s = 0; s <= nst; ++s) {
    if (s < nst && tid < 64) {
      float* buf = hlb_s[s & 1];
      const int t0 = s2 + s * 16;
      float xr[16];
#pragma unroll
      for (int i = 0; i < 16; ++i) xr[i] = xin_s[(t0 + i - s1) * 20 + fch];
#pragma unroll
      for (int i = 0; i < 16; ++i) {
        v3 = fmaf(xr[i] - v3, rt3, v3);
        const float sp = (v3 - th3 >= 0.0f) ? 1.0f : 0.0f;
        if (tid < 60) buf[i * 60 + tid] = sp;
        v3 = (sp != 0.0f) ? 0.0f : v3;
      }
    }
    if (s > 0 && tid >= 64 && cst_ < 9) {
      const float* buf = hlb_s[(s - 1) & 1];
      const int base = (s - 1) * 16;
      const float bias = cb_s[co];
      for (int r = cst_; r < 16; r += 9) {
        const float* hp = buf + r * 60;  // broadcast across the 20 o-lanes
        float acc = bias;
#pragma unroll
        for (int q = 0; q < 15; ++q) {
          const float4 h = *(const float4*)&hp[q * 4];
          acc = fmaf(h.x, wreg[q].x, acc);
          acc = fmaf(h.y, wreg[q].y, acc);
          acc = fmaf(h.z, wreg[q].z, acc);
          acc = fmaf(h.w, wreg[q].w, acc);
        }
        c_s[(base + r) * 20 + co] = acc;
      }
    }
    __syncthreads();
  }

  // ---- P4: lifseq scan (wave 0, 20 chains), 16-step register batches ----
  if (tid < 64) {
    const int f = tid < 20 ? tid : 0;
    const float rt = 1.0f / (float)TAU2d;
    float v = 0.0f;
    for (int t0 = s2; t0 < end; t0 += 16) {
      float xr[16];
#pragma unroll
      for (int i = 0; i < 16; ++i) xr[i] = c_s[(t0 + i - s2) * 20 + f];
#pragma unroll
      for (int i = 0; i < 16; ++i) {
        v = fmaf(xr[i] - v, rt, v);
        const float sp = (v - 0.08f >= 0.0f) ? 1.0f : 0.0f;
        if ((tid < 20) & (t0 + i >= outstart))
          s4_s[(t0 + i - outstart) * 20 + tid] = sp;
        v = (sp != 0.0f) ? 0.0f : v;
      }
    }
  }
  __syncthreads();

  // ---- P5: fcskip -> hlb_s (dead), then coalesced global store ----
  float* res = &hlb_s[0][0];  // HRL*O <= 1280 floats <= 1920 available
  {
    constexpr int ORG = (O == 20) ? 12 : 25;
    const int rg = tid / O;
    const int o = tid - rg * O;
    const int xoff = outstart - s1;
    if (rg < ORG) {
      float4 fv[5], kv[5];
      const float* fwp = fw_s + o * 20;
      const float* swp = skw_s + o * 20;
#pragma unroll
      for (int q = 0; q < 5; ++q) {
        fv[q] = *(const float4*)&fwp[q * 4];
        kv[q] = *(const float4*)&swp[q * 4];
      }
      const float bias = fb_s[o] + skb_s[o];
      for (int rel = rg; rel < HRL; rel += ORG) {
        const float* s = s4_s + rel * 20;            // broadcast rows
        const float* xi = xin_s + (xoff + rel) * 20; // broadcast rows
        float acc = bias;
#pragma unroll
        for (int q = 0; q < 5; ++q) {
          const float4 sv = *(const float4*)&s[q * 4];
          const float4 xv = *(const float4*)&xi[q * 4];
          acc = fmaf(sv.x, fv[q].x, fmaf(xv.x, kv[q].x, acc));
          acc = fmaf(sv.y, fv[q].y, fmaf(xv.y, kv[q].y, acc));
          acc = fmaf(sv.z, fv[q].z, fmaf(xv.z, kv[q].z, acc));
          acc = fmaf(sv.w, fv[q].w, fmaf(xv.w, kv[q].w, acc));
        }
        res[rel * O + o] = acc;
      }
    }
  }
  __syncthreads();
  {
    float4* gout = (float4*)(outp + (size_t)outstart * O);
    for (int i = tid; i < HRL * O / 4; i += 256) gout[i] = ((float4*)res)[i];
  }
}

// K5: final LIF over batch axis: 1000 chains, chunked over b (L=W=32).
__global__ void __launch_bounds__(256) k_flif(const float* __restrict__ out2,
                                              float* __restrict__ out3) {
  const int idx = blockIdx.x * 256 + threadIdx.x;
  if (idx >= FB_NCH * 1000) return;
  const int chunk = idx / 1000;
  const int chain = idx - chunk * 1000;
  const float rt = 1.0f / (float)TAU2d;
  const int outstart = chunk * FB_L;
  const int start = (outstart >= FB_W) ? outstart - FB_W : 0;
  const int end = outstart + FB_L;
  float v = 0.0f;
  float xb[4];
#pragma unroll
  for (int i = 0; i < 4; ++i) xb[i] = out2[(start + i) * 1000 + chain];
#pragma unroll 4
  for (int b = start; b < end; ++b) {
    const float x = xb[b & 3];
    xb[b & 3] = out2[(b + 4) * 1000 + chain];  // over-read harmless (unused)
    v = fmaf(x - v, rt, v);
    const float sp = (v - 0.08f >= 0.0f) ? 1.0f : 0.0f;
    if (b >= outstart) out3[b * 1000 + chain] = sp;
    v = (sp != 0.0f) ? 0.0f : v;
  }
}

// K6: dp -> avg -> fused; per-block (per-b) partial sum/sumsq in double.
__global__ void __launch_bounds__(256) k_fused(const float* __restrict__ out3,
                                               float* __restrict__ fused,
                                               double* __restrict__ stats) {
  __shared__ float dp_s[200];
  __shared__ float avg_s[20];
  __shared__ double red_s[8];
  const int b = blockIdx.x;
  const int tid = threadIdx.x;
  if (tid < 200) {
    const int f = tid / 20;
    const int seg = tid - f * 20;
    const float* base = out3 + b * 1000 + seg * 50 + f;
    dp_s[tid] = ((base[30] + base[40]) - (base[0] + base[10])) * 0.5f;
  }
  __syncthreads();
  if (tid < 20) {
    float s = 0.0f;
#pragma unroll
    for (int f = 0; f < 10; ++f) s += dp_s[f * 20 + tid];
    avg_s[tid] = s / 10.0f;
  }
  __syncthreads();
  float val = 0.0f;
  if (tid < 200) {
    val = dp_s[tid] * avg_s[tid % 20];
    fused[b * 200 + tid] = val;
  }
  double sv = (double)val, sq = (double)val * (double)val;
#pragma unroll
  for (int off = 32; off > 0; off >>= 1) {
    sv += __shfl_down(sv, off);
    sq += __shfl_down(sq, off);
  }
  const int wid = tid >> 6;
  if ((tid & 63) == 0) { red_s[wid * 2] = sv; red_s[wid * 2 + 1] = sq; }
  __syncthreads();
  if (tid == 0) {
    double S = 0.0, Q = 0.0;
#pragma unroll
    for (int w = 0; w < 4; ++w) { S += red_s[w * 2]; Q += red_s[w * 2 + 1]; }
    stats[b * 2] = S;
    stats[b * 2 + 1] = Q;
  }
}

// K7: 8 blocks x 512 thr. Each block redundantly reduces stats (bit-identical
// to the old single-block order: old waves 8-15 contributed exact +0.0), then
// computes 64 logits rows (one thread per row, float4 loads, j-ascending
// accumulation preserved -> bit-identical outputs).
__global__ void __launch_bounds__(512) k_head(const float* __restrict__ fused,
                                              const double* __restrict__ stats,
                                              const float* __restrict__ gamma,
                                              const float* __restrict__ beta,
                                              const float* __restrict__ clsw,
                                              const float* __restrict__ clsb,
                                              float* __restrict__ out) {
  __shared__ double redS[8], redQ[8];
  __shared__ __align__(16) float cls_s[600];
  __shared__ float cb_s[3];
  __shared__ float mr_s[2];
  const int tid = threadIdx.x;
  for (int i = tid; i < 150; i += 512)
    ((float4*)cls_s)[i] = ((const float4*)clsw)[i];
  if (tid < 3) cb_s[tid] = clsb[tid];
  double s = stats[2 * tid], q = stats[2 * tid + 1];
#pragma unroll
  for (int off = 32; off > 0; off >>= 1) {
    s += __shfl_down(s, off);
    q += __shfl_down(q, off);
  }
  const int wid = tid >> 6;
  if ((tid & 63) == 0) { redS[wid] = s; redQ[wid] = q; }
  __syncthreads();
  if (tid == 0) {
    double S = 0.0, Q = 0.0;
#pragma unroll
    for (int w = 0; w < 8; ++w) { S += redS[w]; Q += redQ[w]; }
    const double mean = S / 102400.0;
    const double var = Q / 102400.0 - mean * mean;
    mr_s[0] = (float)mean;
    mr_s[1] = (float)(1.0 / sqrt(var + 1e-5));
  }
  __syncthreads();
  if (tid < 64) {
    const int row = blockIdx.x * 64 + tid;
    const float mean = mr_s[0], rsig = mr_s[1];
    const float ga = gamma[0], be = beta[0];
    const float* fr = fused + (size_t)row * 200;
    float l0 = cb_s[0], l1 = cb_s[1], l2 = cb_s[2];
#pragma unroll 5
    for (int qd = 0; qd < 50; ++qd) {
      const float4 f4 = *(const float4*)&fr[qd * 4];
      const float4 c0 = *(const float4*)&cls_s[qd * 4];
      const float4 c1 = *(const float4*)&cls_s[200 + qd * 4];
      const float4 c2 = *(const float4*)&cls_s[400 + qd * 4];
      const float fa[4] = {f4.x, f4.y, f4.z, f4.w};
      const float ca0[4] = {c0.x, c0.y, c0.z, c0.w};
      const float ca1[4] = {c1.x, c1.y, c1.z, c1.w};
      const float ca2[4] = {c2.x, c2.y, c2.z, c2.w};
#pragma unroll
      for (int e = 0; e < 4; ++e) {
        const float bn = (fa[e] - mean) * rsig * ga + be;
        l0 = fmaf(bn, ca0[e], l0);
        l1 = fmaf(bn, ca1[e], l1);
        l2 = fmaf(bn, ca2[e], l2);
      }
    }
    const float m = fmaxf(l0, fmaxf(l1, l2));
    const float lse = m + logf(expf(l0 - m) + expf(l1 - m) + expf(l2 - m));
    out[row * 3 + 0] = l0 - lse;
    out[row * 3 + 1] = l1 - lse;
    out[row * 3 + 2] = l2 - lse;
  }
}

extern "C" void kernel_launch(void* const* d_in, const int* in_sizes, int n_in,
                              void* d_out, int out_size, void* d_ws, size_t ws_size,
                              hipStream_t stream) {
  (void)in_sizes; (void)n_in; (void)out_size; (void)ws_size;
  const float* x     = (const float*)d_in[0];
  const float* wih   = (const float*)d_in[1];
  const float* whh   = (const float*)d_in[2];
  const float* bih   = (const float*)d_in[3];
  const float* bhh   = (const float*)d_in[4];
  const float* sc_w  = (const float*)d_in[5];
  const float* sc_b  = (const float*)d_in[6];
  const float* c1w   = (const float*)d_in[7];
  const float* c1b   = (const float*)d_in[8];
  const float* f1w   = (const float*)d_in[9];
  const float* f1b   = (const float*)d_in[10];
  const float* k1w   = (const float*)d_in[11];
  const float* k1b   = (const float*)d_in[12];
  const float* c2w   = (const float*)d_in[13];
  const float* c2b   = (const float*)d_in[14];
  const float* f2w   = (const float*)d_in[15];
  const float* f2b   = (const float*)d_in[16];
  const float* k2w   = (const float*)d_in[17];
  const float* k2b   = (const float*)d_in[18];
  const float* gamma = (const float*)d_in[19];
  const float* beta  = (const float*)d_in[20];
  const float* clsw  = (const float*)d_in[21];
  const float* clsb  = (const float*)d_in[22];
  float* out = (float*)d_out;
  float* ws = (float*)d_ws;

  float* pre   = ws + OFF_PRE;
  float* hseq  = ws + OFF_HSEQ;
  float* xin2  = ws + OFF_XIN2;
  float* out2  = ws + OFF_OUT2;
  float* out3  = ws + OFF_OUT3;
  float* fused = ws + OFF_FUSED;
  double* stats = (double*)(ws + OFF_STATS);

  k_pregate<<<512, 256, 0, stream>>>(x, wih, bih, bhh, pre);
  k_lstm<<<LSTM_NCH, 64, 0, stream>>>(pre, whh, hseq);
  k_hr<0, 20><<<HR_NCH, 256, 0, stream>>>(hseq, sc_w, sc_b, c1w, c1b, f1w, f1b,
                                          k1w, k1b, xin2);
  k_hr<1, 10><<<HR_NCH, 256, 0, stream>>>(xin2, nullptr, nullptr, c2w, c2b,
                                          f2w, f2b, k2w, k2b, out2);
  k_flif<<<(FB_NCH * 1000 + 255) / 256, 256, 0, stream>>>(out2, out3);
  k_fused<<<512, 256, 0, stream>>>(out3, fused, stats);
  k_head<<<8, 512, 0, stream>>>(fused, stats, gamma, beta, clsw, clsb, out);
}